// Round 6
// baseline (228.462 us; speedup 1.0000x reference)
//
#include <hip/hip_runtime.h>

// Problem constants (from reference)
#define BATCH   4096
#define NLAB    16384
#define HID     1024
#define REC_PEN 1e-6

// Grid split: blocks [0, NB_BCE) stream BCE; blocks [NB_BCE, NBLK) do edges.
#define NB_BCE 2048
#define NB_REC 512
#define NBLK   (NB_BCE + NB_REC)
#define BLK    256
#define UNROLL 4   // contiguous block tile = UNROLL*BLK float4 = 16 KB

__device__ __forceinline__ float softplus_f(float x) {
    // logaddexp(0, x) = max(x,0) + log(1 + exp(-|x|)); hw exp/log (~1 ulp)
    float e = __expf(-fabsf(x));
    return fmaxf(x, 0.0f) + __logf(1.0f + e);
}

__device__ __forceinline__ float bce4(float4 x, float4 y) {
    float a = softplus_f(x.x) - x.x * y.x;
    float b = softplus_f(x.y) - x.y * y.y;
    float c = softplus_f(x.z) - x.z * y.z;
    float d = softplus_f(x.w) - x.w * y.w;
    return (a + b) + (c + d);
}

// Block-level f32 sum; result valid on threadIdx.x == 0.
__device__ __forceinline__ float block_reduce_f32(float v) {
    #pragma unroll
    for (int off = 32; off > 0; off >>= 1)
        v += __shfl_down(v, off, 64);
    __shared__ float s32[BLK / 64];
    const int wave = threadIdx.x >> 6;
    const int lane = threadIdx.x & 63;
    if (lane == 0) s32[wave] = v;
    __syncthreads();
    float r = 0.0f;
    if (threadIdx.x == 0) {
        #pragma unroll
        for (int i = 0; i < BLK / 64; ++i) r += s32[i];
    }
    return r;
}

// Block-level f64 sum; result valid on threadIdx.x == 0. (for the fused finale)
__device__ __forceinline__ double block_reduce_f64(double v) {
    #pragma unroll
    for (int off = 32; off > 0; off >>= 1)
        v += __shfl_down(v, off, 64);
    __shared__ double s64[BLK / 64];
    const int wave = threadIdx.x >> 6;
    const int lane = threadIdx.x & 63;
    if (lane == 0) s64[wave] = v;
    __syncthreads();
    double r = 0.0;
    if (threadIdx.x == 0) {
        #pragma unroll
        for (int i = 0; i < BLK / 64; ++i) r += s64[i];
    }
    return r;
}

// Fused single-kernel loss:
//  blockIdx.x <  NB_BCE : BCE over contiguous 16KB block tiles (8 loads/iter)
//  blockIdx.x >= NB_BCE : one wave per edge, gather two rows of W
//  every block: write f32 partial (agent-coherent), bump counter; the LAST
//  block re-reduces all partials in f64 (fixed order -> deterministic).
__global__ __launch_bounds__(BLK) void loss_fused_kernel(
        const float4* __restrict__ x4,     // logits as float4
        const float4* __restrict__ y4,     // targets as float4
        const float4* __restrict__ w4,     // recursive_params as float4
        const int*    __restrict__ par,
        const int*    __restrict__ chi,
        float*    partial,                 // [NBLK] in d_ws
        unsigned* cnt,                     // single counter in d_ws (memset 0 per call)
        float*    out,
        int n4, int nedges) {
    float acc = 0.0f;
    if (blockIdx.x < NB_BCE) {
        const int tid     = threadIdx.x;
        const int tile    = BLK * UNROLL;         // 1024 float4 per block-iter
        const int gstride = NB_BCE * tile;
        float acc0 = 0.f, acc1 = 0.f, acc2 = 0.f, acc3 = 0.f;
        int base = blockIdx.x * tile + tid;
        for (; base + 3 * BLK < n4; base += gstride) {
            // 8 independent coalesced loads from two contiguous 16KB regions;
            // compiler-scheduled (explicit sched_group_barrier pinning was a
            // 100us regression in R5 -- m141 failure mode).
            float4 x0 = x4[base];
            float4 x1 = x4[base + BLK];
            float4 x2 = x4[base + 2 * BLK];
            float4 x3 = x4[base + 3 * BLK];
            float4 y0 = y4[base];
            float4 y1 = y4[base + BLK];
            float4 y2 = y4[base + 2 * BLK];
            float4 y3 = y4[base + 3 * BLK];
            acc0 += bce4(x0, y0);
            acc1 += bce4(x1, y1);
            acc2 += bce4(x2, y2);
            acc3 += bce4(x3, y3);
        }
        for (; base < n4; base += BLK)  // tail (empty at this problem size)
            acc0 += bce4(x4[base], y4[base]);
        acc = (acc0 + acc1) + (acc2 + acc3);
    } else {
        const int bid    = blockIdx.x - NB_BCE;
        const int lane   = threadIdx.x & 63;
        const int waveId = (bid * BLK + threadIdx.x) >> 6;
        const int nwaves = (NB_REC * BLK) >> 6;
        for (int e = waveId; e < nedges; e += nwaves) {
            const float4* pr = w4 + (long)par[e] * (HID / 4);
            const float4* cr = w4 + (long)chi[e] * (HID / 4);
            float4 a0 = pr[lane],       a1 = pr[lane + 64];
            float4 a2 = pr[lane + 128], a3 = pr[lane + 192];
            float4 b0 = cr[lane],       b1 = cr[lane + 64];
            float4 b2 = cr[lane + 128], b3 = cr[lane + 192];
            float4 d;
            d.x = a0.x - b0.x; d.y = a0.y - b0.y; d.z = a0.z - b0.z; d.w = a0.w - b0.w;
            acc += d.x * d.x + d.y * d.y + d.z * d.z + d.w * d.w;
            d.x = a1.x - b1.x; d.y = a1.y - b1.y; d.z = a1.z - b1.z; d.w = a1.w - b1.w;
            acc += d.x * d.x + d.y * d.y + d.z * d.z + d.w * d.w;
            d.x = a2.x - b2.x; d.y = a2.y - b2.y; d.z = a2.z - b2.z; d.w = a2.w - b2.w;
            acc += d.x * d.x + d.y * d.y + d.z * d.z + d.w * d.w;
            d.x = a3.x - b3.x; d.y = a3.y - b3.y; d.z = a3.z - b3.z; d.w = a3.w - b3.w;
            acc += d.x * d.x + d.y * d.y + d.z * d.z + d.w * d.w;
        }
    }

    float r = block_reduce_f32(acc);

    // ---- last-block finale (replaces the second kernel) ----
    __shared__ int is_last;
    if (threadIdx.x == 0) {
        // agent-coherent store so other XCDs see it
        __hip_atomic_store(&partial[blockIdx.x], r,
                           __ATOMIC_RELAXED, __HIP_MEMORY_SCOPE_AGENT);
        unsigned old = __hip_atomic_fetch_add(cnt, 1u,
                           __ATOMIC_ACQ_REL, __HIP_MEMORY_SCOPE_AGENT);
        is_last = (old == (unsigned)(NBLK - 1));
    }
    __syncthreads();
    if (!is_last) return;

    // exactly one block reaches here, after all partials are globally visible
    double a = 0.0, b = 0.0;
    for (int i = threadIdx.x; i < NB_BCE; i += BLK)
        a += (double)__hip_atomic_load(&partial[i],
                        __ATOMIC_RELAXED, __HIP_MEMORY_SCOPE_AGENT);
    for (int i = threadIdx.x; i < NB_REC; i += BLK)
        b += (double)__hip_atomic_load(&partial[NB_BCE + i],
                        __ATOMIC_RELAXED, __HIP_MEMORY_SCOPE_AGENT);
    double ra = block_reduce_f64(a);
    __syncthreads();            // s64 reuse hazard between the two reduces
    double rb = block_reduce_f64(b);
    if (threadIdx.x == 0) {
        double bce = ra / ((double)BATCH * (double)NLAB);
        double reg = REC_PEN * 0.5 * rb;
        out[0] = (float)(bce + reg);
    }
}

extern "C" void kernel_launch(void* const* d_in, const int* in_sizes, int n_in,
                              void* d_out, int out_size, void* d_ws, size_t ws_size,
                              hipStream_t stream) {
    const float* logits  = (const float*)d_in[0];
    const float* targets = (const float*)d_in[1];
    const float* wparams = (const float*)d_in[2];
    const int*   par     = (const int*)d_in[3];
    const int*   chi     = (const int*)d_in[4];

    const int n  = in_sizes[0];      // BATCH*NLAB = 67,108,864
    const int n4 = n / 4;
    const int ne = in_sizes[3];      // 16383

    float*    partial = (float*)d_ws;            // NBLK floats
    unsigned* cnt     = (unsigned*)(partial + NBLK);

    // reset the completion counter (graph-capture-safe async memset)
    hipMemsetAsync(cnt, 0, sizeof(unsigned), stream);

    loss_fused_kernel<<<NBLK, BLK, 0, stream>>>(
        (const float4*)logits, (const float4*)targets, (const float4*)wparams,
        par, chi, partial, cnt, (float*)d_out, n4, ne);
}

// Round 7
// 112.624 us; speedup vs baseline: 2.0285x; 2.0285x over previous
//
#include <hip/hip_runtime.h>

// Problem constants (from reference)
#define BATCH   4096
#define NLAB    16384
#define HID     1024
#define REC_PEN 1e-6

// Grid split: blocks [0, NB_BCE) stream BCE; blocks [NB_BCE, NB_BCE+NB_REC) do edges.
#define NB_BCE 2048
#define NB_REC 512
#define BLK    256
#define UNROLL 8   // contiguous block tile = UNROLL*BLK float4 = 32 KB; 4 outer iters

__device__ __forceinline__ float softplus_f(float x) {
    // logaddexp(0, x) = max(x,0) + log(1 + exp(-|x|)); hw exp/log (~1 ulp)
    float e = __expf(-fabsf(x));
    return fmaxf(x, 0.0f) + __logf(1.0f + e);
}

__device__ __forceinline__ float bce4(float4 x, float4 y) {
    float a = softplus_f(x.x) - x.x * y.x;
    float b = softplus_f(x.y) - x.y * y.y;
    float c = softplus_f(x.z) - x.z * y.z;
    float d = softplus_f(x.w) - x.w * y.w;
    return (a + b) + (c + d);
}

// Block-level f32 sum reduction; result valid on threadIdx.x == 0.
__device__ __forceinline__ float block_reduce_f32(float v) {
    #pragma unroll
    for (int off = 32; off > 0; off >>= 1)
        v += __shfl_down(v, off, 64);
    __shared__ float s[BLK / 64];
    const int wave = threadIdx.x >> 6;
    const int lane = threadIdx.x & 63;
    if (lane == 0) s[wave] = v;
    __syncthreads();
    float r = 0.0f;
    if (threadIdx.x == 0) {
        #pragma unroll
        for (int i = 0; i < BLK / 64; ++i) r += s[i];
    }
    return r;
}

// Fused partial-sum kernel (two-kernel structure: the atomic last-block
// finale was a 100us regression in R5/R6 -- agent-scope ACQ_REL atomics
// emit L2 writeback+invalidate per block).
//  blockIdx.x <  NB_BCE : BCE over contiguous 32KB block tiles, 16
//                         independent float4 loads per iteration (MLP).
//  blockIdx.x >= NB_BCE : one wave per edge (grid-stride), gather two rows of W
__global__ __launch_bounds__(BLK) void partials_kernel(
        const float4* __restrict__ x4,     // logits as float4
        const float4* __restrict__ y4,     // targets as float4
        const float4* __restrict__ w4,     // recursive_params as float4
        const int*    __restrict__ par,
        const int*    __restrict__ chi,
        float* __restrict__ partial,       // [NB_BCE + NB_REC]
        int n4, int nedges) {
    float acc = 0.0f;
    if (blockIdx.x < NB_BCE) {
        const int tid     = threadIdx.x;
        const int tile    = BLK * UNROLL;         // 2048 float4 per block-iter
        const int gstride = NB_BCE * tile;        // 4,194,304 float4
        float accs[UNROLL];
        #pragma unroll
        for (int u = 0; u < UNROLL; ++u) accs[u] = 0.0f;
        int base = blockIdx.x * tile + tid;
        for (; base + (UNROLL - 1) * BLK < n4; base += gstride) {
            float4 xv[UNROLL], yv[UNROLL];
            #pragma unroll
            for (int u = 0; u < UNROLL; ++u) xv[u] = x4[base + u * BLK];
            #pragma unroll
            for (int u = 0; u < UNROLL; ++u) yv[u] = y4[base + u * BLK];
            #pragma unroll
            for (int u = 0; u < UNROLL; ++u) accs[u] += bce4(xv[u], yv[u]);
        }
        for (; base < n4; base += BLK)  // tail (empty at this problem size)
            accs[0] += bce4(x4[base], y4[base]);
        #pragma unroll
        for (int u = 1; u < UNROLL; ++u) accs[0] += accs[u];
        acc = accs[0];
    } else {
        const int bid    = blockIdx.x - NB_BCE;
        const int lane   = threadIdx.x & 63;
        const int waveId = (bid * BLK + threadIdx.x) >> 6;
        const int nwaves = (NB_REC * BLK) >> 6;
        for (int e = waveId; e < nedges; e += nwaves) {
            const float4* pr = w4 + (long)par[e] * (HID / 4);
            const float4* cr = w4 + (long)chi[e] * (HID / 4);
            float4 a0 = pr[lane],       a1 = pr[lane + 64];
            float4 a2 = pr[lane + 128], a3 = pr[lane + 192];
            float4 b0 = cr[lane],       b1 = cr[lane + 64];
            float4 b2 = cr[lane + 128], b3 = cr[lane + 192];
            float4 d;
            d.x = a0.x - b0.x; d.y = a0.y - b0.y; d.z = a0.z - b0.z; d.w = a0.w - b0.w;
            acc += d.x * d.x + d.y * d.y + d.z * d.z + d.w * d.w;
            d.x = a1.x - b1.x; d.y = a1.y - b1.y; d.z = a1.z - b1.z; d.w = a1.w - b1.w;
            acc += d.x * d.x + d.y * d.y + d.z * d.z + d.w * d.w;
            d.x = a2.x - b2.x; d.y = a2.y - b2.y; d.z = a2.z - b2.z; d.w = a2.w - b2.w;
            acc += d.x * d.x + d.y * d.y + d.z * d.z + d.w * d.w;
            d.x = a3.x - b3.x; d.y = a3.y - b3.y; d.z = a3.z - b3.z; d.w = a3.w - b3.w;
            acc += d.x * d.x + d.y * d.y + d.z * d.z + d.w * d.w;
        }
    }
    float r = block_reduce_f32(acc);
    if (threadIdx.x == 0) partial[blockIdx.x] = r;
}

// Single-block final reduce in f64 (deterministic, no atomics).
__global__ __launch_bounds__(BLK) void final_reduce_kernel(
        const float* __restrict__ partial, float* __restrict__ out) {
    double a = 0.0, b = 0.0;
    for (int i = threadIdx.x; i < NB_BCE; i += BLK) a += (double)partial[i];
    for (int i = threadIdx.x; i < NB_REC; i += BLK) b += (double)partial[NB_BCE + i];
    __shared__ double sa[BLK], sb[BLK];
    sa[threadIdx.x] = a;
    sb[threadIdx.x] = b;
    __syncthreads();
    for (int off = BLK / 2; off > 0; off >>= 1) {
        if (threadIdx.x < off) {
            sa[threadIdx.x] += sa[threadIdx.x + off];
            sb[threadIdx.x] += sb[threadIdx.x + off];
        }
        __syncthreads();
    }
    if (threadIdx.x == 0) {
        double bce = sa[0] / ((double)BATCH * (double)NLAB);
        double reg = REC_PEN * 0.5 * sb[0];
        out[0] = (float)(bce + reg);
    }
}

extern "C" void kernel_launch(void* const* d_in, const int* in_sizes, int n_in,
                              void* d_out, int out_size, void* d_ws, size_t ws_size,
                              hipStream_t stream) {
    const float* logits  = (const float*)d_in[0];
    const float* targets = (const float*)d_in[1];
    const float* wparams = (const float*)d_in[2];
    const int*   par     = (const int*)d_in[3];
    const int*   chi     = (const int*)d_in[4];

    const int n  = in_sizes[0];      // BATCH*NLAB = 67,108,864
    const int n4 = n / 4;
    const int ne = in_sizes[3];      // 16383

    float* partial = (float*)d_ws;   // (NB_BCE + NB_REC) * 4 bytes

    partials_kernel<<<NB_BCE + NB_REC, BLK, 0, stream>>>(
        (const float4*)logits, (const float4*)targets, (const float4*)wparams,
        par, chi, partial, n4, ne);

    final_reduce_kernel<<<1, BLK, 0, stream>>>(partial, (float*)d_out);
}